// Round 1
// baseline (922.453 us; speedup 1.0000x reference)
//
#include <hip/hip_runtime.h>

typedef unsigned short u16;
typedef short s16x4 __attribute__((ext_vector_type(4)));
typedef short s16x8 __attribute__((ext_vector_type(8)));
typedef float f32x4 __attribute__((ext_vector_type(4)));

#define DEVFN __device__ __forceinline__

// problem constants
constexpr long AW_OFF  = 4194304;               // attn_output elems (2*2048*1024)
constexpr long PAT_OFF = AW_OFF + 134217728;    // + attn_weights elems (2*16*2048*2048)

DEVFN u16 f2bf(float x) {
  unsigned u = __builtin_bit_cast(unsigned, x);
  unsigned r = (u + 0x7fffu + ((u >> 16) & 1u)) >> 16;   // RNE
  return (u16)r;
}

// ---------------- fp32 -> bf16 elementwise ----------------
__global__ __launch_bounds__(256) void k_cvt(const float* __restrict__ in,
                                             u16* __restrict__ out, int n4) {
  int i = blockIdx.x * 256 + threadIdx.x;
  if (i >= n4) return;
  float4 v = ((const float4*)in)[i];
  s16x4 o; o[0] = f2bf(v.x); o[1] = f2bf(v.y); o[2] = f2bf(v.z); o[3] = f2bf(v.w);
  ((s16x4*)out)[i] = o;
}

// ---------------- tiled transpose: out[n][k] = bf16(in[k][n]) ----------------
// grid: (N/32, K/32, Z), block (32,8)
template <bool IN_F32>
__global__ __launch_bounds__(256) void k_tr(const void* __restrict__ inv,
                                            u16* __restrict__ out,
                                            long ldin, long ldout,
                                            long inz1, long inz2, long outz, int zdiv) {
  __shared__ u16 tile[32][33];
  int z = blockIdx.z;
  long ioff = (long)(z / zdiv) * inz1 + (long)(z % zdiv) * inz2;
  int k0 = blockIdx.y * 32, n0 = blockIdx.x * 32;
  int tx = threadIdx.x, ty = threadIdx.y;
#pragma unroll
  for (int i = 0; i < 4; ++i) {
    long k = k0 + ty + i * 8, n = n0 + tx;
    u16 v;
    if constexpr (IN_F32) v = f2bf(((const float*)inv)[ioff + k * ldin + n]);
    else                  v = ((const u16*)inv)[ioff + k * ldin + n];
    tile[ty + i * 8][tx] = v;
  }
  __syncthreads();
  long ooff = (long)z * outz;
#pragma unroll
  for (int i = 0; i < 4; ++i) {
    long n = n0 + ty + i * 8, k = k0 + tx;
    out[ooff + n * ldout + k] = tile[tx][ty + i * 8];
  }
}

// ---------------- batched NT GEMM: C = alpha * A[M,K] @ B[N,K]^T + bias ----------------
// A: bf16 (or fp32 if A_F32, converted during staging), B: bf16, C: fp32 or bf16.
// z decomposed as z1 = z/zdiv, z2 = z%zdiv with separate pointer strides.
// 256 threads = 4 waves in 2x2; wave tile (BM/2, BN/2); mfma 16x16x32 bf16.
template <typename OutT, bool A_F32, int BM, int BN, int BK>
__global__ __launch_bounds__(256) void k_gemm_nt(
    const void* __restrict__ Av, const u16* __restrict__ Bp, OutT* __restrict__ Cp,
    const float* __restrict__ bias, float alpha, int K,
    long lda, long ldb, long ldc,
    long saz1, long saz2, long sbz1, long sbz2, long scz1, long scz2,
    long sbias, int zdiv) {
  constexpr int BKP = BK + 8;   // 72 -> 144B row pitch: 16B aligned, 2-way-only bank aliasing
  __shared__ __align__(16) u16 At[BM][BKP];
  __shared__ __align__(16) u16 Bt[BN][BKP];

  const int tid = threadIdx.x;
  const int lane = tid & 63;
  const int wid = tid >> 6;
  const int wm = wid >> 1, wn = wid & 1;
  constexpr int WM = BM / 2, WN = BN / 2;
  constexpr int FM = WM / 16, FN = WN / 16;

  const int z = blockIdx.z, z1 = z / zdiv, z2 = z % zdiv;
  const long aoff = (long)z1 * saz1 + (long)z2 * saz2;
  const long boff = (long)z1 * sbz1 + (long)z2 * sbz2;
  const long coff = (long)z1 * scz1 + (long)z2 * scz2;
  const u16* Ab = A_F32 ? nullptr : (const u16*)Av + aoff;
  const float* Af = A_F32 ? (const float*)Av + aoff : nullptr;
  const u16* Bb = Bp + boff;
  OutT* C = Cp + coff;
  const float* bz = bias ? bias + (long)z * sbias : nullptr;

  const int row0 = blockIdx.y * BM, col0 = blockIdx.x * BN;

  f32x4 acc[FM][FN] = {};

  for (int k0 = 0; k0 < K; k0 += BK) {
    // stage A tile (BM x BK)
#pragma unroll
    for (int it = 0; it < (BM * BK) / (256 * 8); ++it) {
      int idx = (it * 256 + tid) * 8;
      int r = idx / BK, c = idx % BK;
      if constexpr (A_F32) {
        const float* s = Af + (long)(row0 + r) * lda + (k0 + c);
        float4 v0 = *(const float4*)s;
        float4 v1 = *(const float4*)(s + 4);
        s16x8 w;
        w[0] = f2bf(v0.x); w[1] = f2bf(v0.y); w[2] = f2bf(v0.z); w[3] = f2bf(v0.w);
        w[4] = f2bf(v1.x); w[5] = f2bf(v1.y); w[6] = f2bf(v1.z); w[7] = f2bf(v1.w);
        *(s16x8*)&At[r][c] = w;
      } else {
        *(s16x8*)&At[r][c] = *(const s16x8*)(Ab + (long)(row0 + r) * lda + (k0 + c));
      }
    }
    // stage B tile (BN x BK)
#pragma unroll
    for (int it = 0; it < (BN * BK) / (256 * 8); ++it) {
      int idx = (it * 256 + tid) * 8;
      int r = idx / BK, c = idx % BK;
      *(s16x8*)&Bt[r][c] = *(const s16x8*)(Bb + (long)(col0 + r) * ldb + (k0 + c));
    }
    __syncthreads();
#pragma unroll
    for (int kk = 0; kk < BK / 32; ++kk) {
      const int kg = kk * 32 + ((lane >> 4) << 2);
      s16x8 af[FM], bfr[FN];
#pragma unroll
      for (int m = 0; m < FM; ++m) {
        const u16* p = &At[wm * WM + m * 16 + (lane & 15)][kg];
        s16x4 lo = *(const s16x4*)p;
        s16x4 hi = *(const s16x4*)(p + 16);
        s16x8 a;
        a[0] = lo[0]; a[1] = lo[1]; a[2] = lo[2]; a[3] = lo[3];
        a[4] = hi[0]; a[5] = hi[1]; a[6] = hi[2]; a[7] = hi[3];
        af[m] = a;
      }
#pragma unroll
      for (int n = 0; n < FN; ++n) {
        const u16* p = &Bt[wn * WN + n * 16 + (lane & 15)][kg];
        s16x4 lo = *(const s16x4*)p;
        s16x4 hi = *(const s16x4*)(p + 16);
        s16x8 b;
        b[0] = lo[0]; b[1] = lo[1]; b[2] = lo[2]; b[3] = lo[3];
        b[4] = hi[0]; b[5] = hi[1]; b[6] = hi[2]; b[7] = hi[3];
        bfr[n] = b;
      }
#pragma unroll
      for (int m = 0; m < FM; ++m)
#pragma unroll
        for (int n = 0; n < FN; ++n)
          acc[m][n] = __builtin_amdgcn_mfma_f32_16x16x32_bf16(af[m], bfr[n], acc[m][n], 0, 0, 0);
    }
    __syncthreads();
  }

  // epilogue: D mapping col=lane&15, row=(lane>>4)*4+reg
#pragma unroll
  for (int m = 0; m < FM; ++m) {
    const int grow = row0 + wm * WM + m * 16 + ((lane >> 4) << 2);
#pragma unroll
    for (int n = 0; n < FN; ++n) {
      const int gcol = col0 + wn * WN + n * 16 + (lane & 15);
      const float bv = bz ? bz[gcol] : 0.0f;
#pragma unroll
      for (int r = 0; r < 4; ++r) {
        float v = alpha * acc[m][n][r] + bv;
        if constexpr (sizeof(OutT) == 2) C[(long)(grow + r) * ldc + gcol] = f2bf(v);
        else                             C[(long)(grow + r) * ldc + gcol] = v;
      }
    }
  }
}

// ---------------- in-place row softmax, rows of 2048 fp32 ----------------
__global__ __launch_bounds__(256) void k_softmax(float* __restrict__ base) {
  float* p = base + (long)blockIdx.x * 2048;
  const int t = threadIdx.x;
  float4 v0 = ((const float4*)p)[t];
  float4 v1 = ((const float4*)p)[t + 256];
  float m = fmaxf(fmaxf(fmaxf(v0.x, v0.y), fmaxf(v0.z, v0.w)),
                  fmaxf(fmaxf(v1.x, v1.y), fmaxf(v1.z, v1.w)));
#pragma unroll
  for (int i = 32; i >= 1; i >>= 1) m = fmaxf(m, __shfl_xor(m, i, 64));
  __shared__ float sm[4], ss[4];
  if ((t & 63) == 0) sm[t >> 6] = m;
  __syncthreads();
  m = fmaxf(fmaxf(sm[0], sm[1]), fmaxf(sm[2], sm[3]));
  float4 e0, e1;
  e0.x = __expf(v0.x - m); e0.y = __expf(v0.y - m); e0.z = __expf(v0.z - m); e0.w = __expf(v0.w - m);
  e1.x = __expf(v1.x - m); e1.y = __expf(v1.y - m); e1.z = __expf(v1.z - m); e1.w = __expf(v1.w - m);
  float s = (e0.x + e0.y + e0.z + e0.w) + (e1.x + e1.y + e1.z + e1.w);
#pragma unroll
  for (int i = 32; i >= 1; i >>= 1) s += __shfl_xor(s, i, 64);
  if ((t & 63) == 0) ss[t >> 6] = s;
  __syncthreads();
  s = ss[0] + ss[1] + ss[2] + ss[3];
  float inv = 1.0f / s;
  e0.x *= inv; e0.y *= inv; e0.z *= inv; e0.w *= inv;
  e1.x *= inv; e1.y *= inv; e1.z *= inv; e1.w *= inv;
  ((float4*)p)[t] = e0;
  ((float4*)p)[t + 256] = e1;
}

// ---------------- launch ----------------
extern "C" void kernel_launch(void* const* d_in, const int* in_sizes, int n_in,
                              void* d_out, int out_size, void* d_ws, size_t ws_size,
                              hipStream_t stream) {
  const float* query = (const float*)d_in[0];
  const float* key   = (const float*)d_in[1];
  const float* value = (const float*)d_in[2];
  const float* Wq = (const float*)d_in[3];
  const float* bq = (const float*)d_in[4];
  const float* Wk = (const float*)d_in[5];
  const float* bk = (const float*)d_in[6];
  const float* Wv = (const float*)d_in[7];
  const float* bv = (const float*)d_in[8];
  const float* Wo = (const float*)d_in[9];
  const float* bo = (const float*)d_in[10];
  const float* Wa = (const float*)d_in[11];
  const float* ba = (const float*)d_in[12];
  float* out = (float*)d_out;
  char* ws = (char*)d_ws;

  // workspace layout (bytes)
  u16* qb  = (u16*)(ws + 0);           // [4096,1024] bf16 query
  u16* kb  = (u16*)(ws + 8388608);
  u16* vb  = (u16*)(ws + 16777216);
  u16* Wqt = (u16*)(ws + 25165824);    // [1024,1024] W^T bf16
  u16* Wkt = (u16*)(ws + 27262976);
  u16* Wvt = (u16*)(ws + 29360128);
  u16* Wot = (u16*)(ws + 31457280);
  u16* Wat = (u16*)(ws + 33554432);    // [3,1024,1024]
  u16* qp  = (u16*)(ws + 39845888);    // [4096,1024] projected q
  u16* kp  = (u16*)(ws + 48234496);
  u16* vp  = (u16*)(ws + 56623104);
  u16* vt  = (u16*)(ws + 65011712);    // [B,H,64,2048] V^T per head
  u16* ctx = (u16*)(ws + 73400320);    // [4096,1024]
  u16* qa  = (u16*)(ws + 81788928);    // [3,4096,1024] aspect q
  u16* ka  = (u16*)(ws + 106954752);   // [3,4096,1024] aspect k

  dim3 b256(256);
  dim3 trb(32, 8);

  // bf16 conversions of activations
  k_cvt<<<4096, b256, 0, stream>>>(query, qb, 1048576);
  k_cvt<<<4096, b256, 0, stream>>>(key,   kb, 1048576);
  k_cvt<<<4096, b256, 0, stream>>>(value, vb, 1048576);

  // weight transposes (fp32 -> bf16, [N,K])
  k_tr<true><<<dim3(32, 32, 1), trb, 0, stream>>>(Wq, Wqt, 1024, 1024, 0, 0, 0, 1);
  k_tr<true><<<dim3(32, 32, 1), trb, 0, stream>>>(Wk, Wkt, 1024, 1024, 0, 0, 0, 1);
  k_tr<true><<<dim3(32, 32, 1), trb, 0, stream>>>(Wv, Wvt, 1024, 1024, 0, 0, 0, 1);
  k_tr<true><<<dim3(32, 32, 1), trb, 0, stream>>>(Wo, Wot, 1024, 1024, 0, 0, 0, 1);
  k_tr<true><<<dim3(32, 32, 3), trb, 0, stream>>>(Wa, Wat, 1024, 1024, 0, 1048576, 1048576, 3);

  // Q/K/V projections -> bf16 [4096,1024]
  k_gemm_nt<u16, false, 128, 128, 64><<<dim3(8, 32, 1), b256, 0, stream>>>(
      qb, Wqt, qp, bq, 1.0f, 1024, 1024, 1024, 1024, 0, 0, 0, 0, 0, 0, 0, 1);
  k_gemm_nt<u16, false, 128, 128, 64><<<dim3(8, 32, 1), b256, 0, stream>>>(
      kb, Wkt, kp, bk, 1.0f, 1024, 1024, 1024, 1024, 0, 0, 0, 0, 0, 0, 0, 1);
  k_gemm_nt<u16, false, 128, 128, 64><<<dim3(8, 32, 1), b256, 0, stream>>>(
      vb, Wvt, vp, bv, 1.0f, 1024, 1024, 1024, 1024, 0, 0, 0, 0, 0, 0, 0, 1);

  // aspect projections, z = aspect (3)
  k_gemm_nt<u16, false, 128, 128, 64><<<dim3(8, 32, 3), b256, 0, stream>>>(
      qb, Wat, qa, ba, 1.0f, 1024, 1024, 1024, 1024,
      0, 0, 0, 1048576, 0, 4194304, 1024, 3);
  k_gemm_nt<u16, false, 128, 128, 64><<<dim3(8, 32, 3), b256, 0, stream>>>(
      kb, Wat, ka, ba, 1.0f, 1024, 1024, 1024, 1024,
      0, 0, 0, 1048576, 0, 4194304, 1024, 3);

  // per-head QK^T logits -> d_out attn_weights region (z = b*16+h)
  k_gemm_nt<float, false, 128, 128, 64><<<dim3(16, 16, 32), b256, 0, stream>>>(
      qp, kp, out + AW_OFF, nullptr, 0.125f, 64, 1024, 1024, 2048,
      2097152, 64, 2097152, 64, 67108864, 4194304, 0, 16);

  // full-dim pattern logits -> d_out patterns region (z = a*2+b)
  k_gemm_nt<float, false, 128, 128, 64><<<dim3(16, 16, 6), b256, 0, stream>>>(
      qa, ka, out + PAT_OFF, nullptr, 0.125f, 1024, 1024, 1024, 2048,
      0, 2097152, 0, 2097152, 0, 4194304, 0, 6);

  // softmax over attn_weights + patterns (contiguous 77824 rows of 2048)
  k_softmax<<<77824, b256, 0, stream>>>(out + AW_OFF);

  // per-head V^T: vt[b,h][d][s]  (z = b*16+h)
  k_tr<false><<<dim3(2, 64, 32), trb, 0, stream>>>(
      vp, vt, 1024, 2048, 2097152, 64, 131072, 16);

  // ctx = P @ V  (A = softmaxed weights fp32, B = vt), out bf16 [4096,1024]
  k_gemm_nt<u16, true, 128, 64, 64><<<dim3(1, 16, 32), b256, 0, stream>>>(
      out + AW_OFF, vt, ctx, nullptr, 1.0f, 2048, 2048, 2048, 1024,
      67108864, 4194304, 2097152, 131072, 2097152, 64, 0, 16);

  // output projection -> d_out attn_output
  k_gemm_nt<float, false, 128, 128, 64><<<dim3(8, 32, 1), b256, 0, stream>>>(
      ctx, Wot, out, bo, 1.0f, 1024, 1024, 1024, 1024, 0, 0, 0, 0, 0, 0, 0, 1);
}